// Round 12
// baseline (877.981 us; speedup 1.0000x reference)
//
#include <hip/hip_runtime.h>
#include <stdint.h>

// Problem constants (MambaBlock: B=8, C=d=1024, H*W=L=1024, depth=4, S=128)
#define DT_STEP 0.001f
#define LN_EPS  1e-5f
#define Bn      8
#define Lseq    1024
#define Dm      1024
#define Sn      128
#define DEPTH   4
#define Mrows   (Bn * Lseq)       // 8192
#define Qc      32                // scan chunk size (R12: back to 32 — depth Qc+NCHUNK min)
#define NCHUNK  (Lseq / Qc)       // 32
#define NPOW    33                // powers 0..32 per layer

typedef short bf16x8 __attribute__((ext_vector_type(8)));
typedef float f32x4  __attribute__((ext_vector_type(4)));

__device__ __forceinline__ unsigned short f2bf(float f) {
    unsigned int u = __float_as_uint(f);
    u += 0x7fffu + ((u >> 16) & 1u);          // round-to-nearest-even
    return (unsigned short)(u >> 16);
}

// async 16B global->LDS (wave-uniform LDS base + lane*16; slot linear in lane)
#define GLOAD_LDS16(gp, lp)                                                \
    __builtin_amdgcn_global_load_lds(                                      \
        (const __attribute__((address_space(1))) unsigned int*)(gp),       \
        (__attribute__((address_space(3))) unsigned int*)(lp), 16, 0, 0)

// ---------------------------------------------------------------------------
// Merged precompute: converts + small dot products.  [R9-verified]
// ---------------------------------------------------------------------------
__global__ __launch_bounds__(256) void prep_conv(const float* __restrict__ Wo,
                                                 const float* __restrict__ Dp,
                                                 const float* __restrict__ Bp,
                                                 const float* __restrict__ bi,
                                                 const float* __restrict__ bo,
                                                 unsigned short* __restrict__ Woh,
                                                 unsigned short* __restrict__ Wo2h,
                                                 unsigned short* __restrict__ Bph,
                                                 float* __restrict__ c2dt,
                                                 float* __restrict__ boeff) {
    int z = blockIdx.y;
    int bx = blockIdx.x;
    int tid = threadIdx.x;
    if (bx < 1024) {
        int i = (bx * 256 + tid) * 4;                   // within z's 1M elems
        const float* S = Wo + (size_t)z * Dm * Dm;
        float4 v = *(const float4*)(S + i);
        int c = i & (Dm - 1);
        float4 d = *(const float4*)(Dp + (size_t)z * Dm + c);
        ushort4 o1, o2;
        o1.x = f2bf(v.x); o1.y = f2bf(v.y); o1.z = f2bf(v.z); o1.w = f2bf(v.w);
        o2.x = f2bf(v.x * d.x); o2.y = f2bf(v.y * d.y);
        o2.z = f2bf(v.z * d.z); o2.w = f2bf(v.w * d.w);
        *(ushort4*)(Woh  + (size_t)z * Dm * Dm + i) = o1;
        *(ushort4*)(Wo2h + (size_t)z * Dm * Dm + i) = o2;
        return;
    } else if (bx < 1152) {
        int i = ((bx - 1024) * 256 + tid) * 4;          // 128 blks * 1024 = Sn*Dm
        float4 v = *(const float4*)(Bp + (size_t)z * Sn * Dm + i);
        ushort4 o;
        o.x = f2bf(v.x); o.y = f2bf(v.y); o.z = f2bf(v.z); o.w = f2bf(v.w);
        *(ushort4*)(Bph + (size_t)z * Sn * Dm + i) = o;
        return;
    }
    // dot-product section
    int j = bx - 1152;
    float acc;
    if (j < Sn) {
        const float* br = Bp + ((size_t)z * Sn + j) * Dm;
        const float* bb = bi + (size_t)z * Dm;
        float4 v = *(const float4*)(br + tid * 4);
        float4 w = *(const float4*)(bb + tid * 4);
        acc = v.x * w.x + v.y * w.y + v.z * w.z + v.w * w.w;
    } else {
        int c = j - Sn;
        const float* wr = Wo + ((size_t)z * Dm + c) * Dm;
        const float* dp = Dp + (size_t)z * Dm;
        const float* bb = bi + (size_t)z * Dm;
        float4 w = *(const float4*)(wr + tid * 4);
        float4 d = *(const float4*)(dp + tid * 4);
        float4 b = *(const float4*)(bb + tid * 4);
        acc = w.x * d.x * b.x + w.y * d.y * b.y + w.z * d.z * b.z + w.w * d.w * b.w;
    }
#pragma unroll
    for (int off = 32; off > 0; off >>= 1) acc += __shfl_down(acc, off, 64);
    __shared__ float red[4];
    if ((tid & 63) == 0) red[tid >> 6] = acc;
    __syncthreads();
    if (tid == 0) {
        float tot = red[0] + red[1] + red[2] + red[3];
        if (j < Sn) c2dt[z * Sn + j] = DT_STEP * tot;
        else        boeff[(size_t)z * Dm + (j - Sn)] = bo[(size_t)z * Dm + (j - Sn)] + tot;
    }
}

// ---------------------------------------------------------------------------
// Merged transpose+convert for Wi (1024x1024) and Cp (1024x128), batched z.
// ---------------------------------------------------------------------------
__global__ __launch_bounds__(256) void transpose_pre(const float* __restrict__ Wi,
                                                     unsigned short* __restrict__ WiTh,
                                                     const float* __restrict__ Cp,
                                                     unsigned short* __restrict__ CpTh) {
    __shared__ float t[32][33];
    int z = blockIdx.z;
    const float* S;
    unsigned short* D;
    int R, C, r0, c0;
    if ((int)blockIdx.x < 32) {
        S = Wi + (size_t)z * Dm * Dm;  D = WiTh + (size_t)z * Dm * Dm;
        R = Dm; C = Dm;
        r0 = blockIdx.y * 32; c0 = blockIdx.x * 32;
    } else {
        S = Cp + (size_t)z * Dm * Sn;  D = CpTh + (size_t)z * Dm * Sn;
        R = Dm; C = Sn;
        r0 = blockIdx.y * 32; c0 = (blockIdx.x - 32) * 32;
    }
    int tx = threadIdx.x & 31, ty = threadIdx.x >> 5;   // 32 x 8
    for (int rr = ty; rr < 32; rr += 8)
        t[rr][tx] = S[(size_t)(r0 + rr) * C + c0 + tx];
    __syncthreads();
    for (int rr = ty; rr < 32; rr += 8)
        D[(size_t)(c0 + rr) * R + r0 + tx] = f2bf(t[tx][rr]);
}

// ---------------------------------------------------------------------------
// Batched 1024x1024 transpose fp32: dst[b][i][j] = src[b][j][i]
// ---------------------------------------------------------------------------
__global__ __launch_bounds__(1024) void transpose_bll(const float* __restrict__ src,
                                                      float* __restrict__ dst) {
    __shared__ float tile[32][33];
    int b  = blockIdx.z;
    int i0 = blockIdx.y * 32, j0 = blockIdx.x * 32;
    int tx = threadIdx.x, ty = threadIdx.y;
    const float* S = src + (size_t)b * Dm * Lseq;
    float*       D = dst + (size_t)b * Dm * Lseq;
    tile[ty][tx] = S[(size_t)(j0 + ty) * 1024 + i0 + tx];
    __syncthreads();
    D[(size_t)(i0 + ty) * 1024 + j0 + tx] = tile[tx][ty];
}

// ---------------------------------------------------------------------------
// FUSED LayerNorm + ub-GEMM (verified R5). 256 blocks x 512 thr; 32 rows/block.
// ---------------------------------------------------------------------------
__global__ __launch_bounds__(512) void ln_ub(
    const float* __restrict__ seq,
    unsigned short* __restrict__ nbuf,
    const unsigned short* __restrict__ M2,
    float* __restrict__ ub,
    const float* __restrict__ gam,
    const float* __restrict__ bet,
    const float* __restrict__ c2dtL) {
    __shared__ __align__(16) unsigned short As[256 * 8];   //  4 KB
    __shared__ __align__(16) unsigned short Bs[1024 * 8];  // 16 KB
    __shared__ float mrow[32], rrow[32];
    int row0 = blockIdx.x * 32;
    int tid = threadIdx.x;

    // ---- Phase A: stats, 16 threads per row ----
    {
        int r = tid >> 4, l = tid & 15;
        const float* xr = seq + (size_t)(row0 + r) * Dm + l * 4;
        float s = 0.f, ss = 0.f;
#pragma unroll
        for (int j = 0; j < 16; j++) {
            float4 v = *(const float4*)(xr + j * 64);
            s  += v.x + v.y + v.z + v.w;
            ss += v.x * v.x + v.y * v.y + v.z * v.z + v.w * v.w;
        }
        s += __shfl_xor(s, 1, 16);  ss += __shfl_xor(ss, 1, 16);
        s += __shfl_xor(s, 2, 16);  ss += __shfl_xor(ss, 2, 16);
        s += __shfl_xor(s, 4, 16);  ss += __shfl_xor(ss, 4, 16);
        s += __shfl_xor(s, 8, 16);  ss += __shfl_xor(ss, 8, 16);
        if (l == 0) {
            float mean = s / (float)Dm;
            float var  = ss / (float)Dm - mean * mean;
            mrow[r] = mean;
            rrow[r] = rsqrtf(var + LN_EPS);
        }
    }
    __syncthreads();
    // ---- Phase A2: normalize -> nbuf (coalesced 16B stores)
#pragma unroll
    for (int g = 0; g < 8; g++) {
        int gi = tid + g * 512;              // 0..4095 = 32 rows x 128 granules
        int rA = gi >> 7, gc = gi & 127;
        int col = gc * 8;
        const float* p = seq + (size_t)(row0 + rA) * Dm + col;
        float4 v0 = *(const float4*)(p);
        float4 v1 = *(const float4*)(p + 4);
        float m = mrow[rA], rs = rrow[rA];
        float4 g0 = *(const float4*)(gam + col);
        float4 g1 = *(const float4*)(gam + col + 4);
        float4 b0 = *(const float4*)(bet + col);
        float4 b1 = *(const float4*)(bet + col + 4);
        bf16x8 pk;
        pk[0] = (short)f2bf((v0.x - m) * rs * g0.x + b0.x);
        pk[1] = (short)f2bf((v0.y - m) * rs * g0.y + b0.y);
        pk[2] = (short)f2bf((v0.z - m) * rs * g0.z + b0.z);
        pk[3] = (short)f2bf((v0.w - m) * rs * g0.w + b0.w);
        pk[4] = (short)f2bf((v1.x - m) * rs * g1.x + b1.x);
        pk[5] = (short)f2bf((v1.y - m) * rs * g1.y + b1.y);
        pk[6] = (short)f2bf((v1.z - m) * rs * g1.z + b1.z);
        pk[7] = (short)f2bf((v1.w - m) * rs * g1.w + b1.w);
        *(bf16x8*)(nbuf + (size_t)(row0 + rA) * Dm + col) = pk;
    }
    __syncthreads();   // drains global stores (vmcnt 0) before async reads

    // ---- Phase B: ub-GEMM on own rows ----
    int wave = tid >> 6, lane = tid & 63;
    int wn = wave * 16;
    int lr = lane & 15, lq = lane >> 4;

    int rowA = tid >> 3;                        // 0..31 for tid<256
    int kclA = (tid & 7) ^ ((tid >> 3) & 7);
    int rowS[2], kclS[2], slotOff[2];
#pragma unroll
    for (int q = 0; q < 2; q++) {
        int s = tid + q * 512;
        rowS[q] = s >> 3;
        kclS[q] = (s & 7) ^ ((s >> 3) & 7);
        slotOff[q] = s * 8;
    }
    int aoff[2][2], boff[2];
#pragma unroll
    for (int i = 0; i < 2; i++)
#pragma unroll
        for (int h = 0; h < 2; h++) {
            int ra = i * 16 + lr;
            aoff[i][h] = (ra * 8 + ((lq + 4 * h) ^ (ra & 7))) * 8;
        }
#pragma unroll
    for (int h = 0; h < 2; h++) {
        int rn = wn + lr;
        boff[h] = (rn * 8 + ((lq + 4 * h) ^ (rn & 7))) * 8;
    }

    f32x4 acc[2];
#pragma unroll
    for (int i = 0; i < 2; i++) acc[i] = (f32x4){0.f, 0.f, 0.f, 0.f};

    for (int k0 = 0; k0 < Dm; k0 += 64) {
        const unsigned short* Abr = nbuf + (size_t)row0 * Dm + k0;
        const unsigned short* Bbr = M2 + k0;
        __syncthreads();
        if (tid < 256)
            GLOAD_LDS16(Abr + (size_t)rowA * Dm + kclA * 8, &As[tid * 8]);
#pragma unroll
        for (int q = 0; q < 2; q++)
            GLOAD_LDS16(Bbr + (size_t)rowS[q] * Dm + kclS[q] * 8, &Bs[slotOff[q]]);
        __syncthreads();
#pragma unroll
        for (int h = 0; h < 2; h++) {
            bf16x8 af[2], bfr;
#pragma unroll
            for (int i = 0; i < 2; i++) af[i] = *(const bf16x8*)&As[aoff[i][h]];
            bfr = *(const bf16x8*)&Bs[boff[h]];
#pragma unroll
            for (int i = 0; i < 2; i++)
                acc[i] = __builtin_amdgcn_mfma_f32_16x16x32_bf16(af[i], bfr,
                                                                 acc[i], 0, 0, 0);
        }
    }
#pragma unroll
    for (int i = 0; i < 2; i++)
#pragma unroll
        for (int r = 0; r < 4; r++) {
            int row = row0 + i * 16 + lq * 4 + r;
            int col = wn + lr;
            ub[(size_t)row * Sn + col] = acc[i][r] + c2dtL[col];
        }
}

// ---------------------------------------------------------------------------
// 128x64-tile residual GEMM body: C(8192x1024 fp32) += A @ B^T (+ bias).
// RMW on C: tiles touching the same C elements must NEVER share a launch.
// ---------------------------------------------------------------------------
__device__ __forceinline__ void gemm64_body(
    int flat, unsigned short* As, unsigned short* Bs,
    const unsigned short* __restrict__ A, const unsigned short* __restrict__ B,
    float* __restrict__ C, const float* __restrict__ bias, int K) {
    int rb = flat & 63, cb = flat >> 6;
    int row0 = rb * 128, col0 = cb * 64;
    int tid  = threadIdx.x;
    int wave = tid >> 6, lane = tid & 63;
    int wm = (wave & 1) * 64, wn = (wave >> 1) * 16;
    int lr = lane & 15, lq = lane >> 4;

    int rowS[2], kclS[2], slotOff[2];
#pragma unroll
    for (int q = 0; q < 2; q++) {
        int s = tid + q * 512;
        rowS[q] = s >> 3;
        kclS[q] = (s & 7) ^ ((s >> 3) & 7);
        slotOff[q] = s * 8;
    }
    int rowB = tid >> 3;
    int kclB = (tid & 7) ^ ((tid >> 3) & 7);

    int aoff[4][2], boff[2];
#pragma unroll
    for (int i = 0; i < 4; i++)
#pragma unroll
        for (int h = 0; h < 2; h++) {
            int ra = wm + i * 16 + lr;
            aoff[i][h] = (ra * 8 + ((lq + 4 * h) ^ (ra & 7))) * 8;
        }
#pragma unroll
    for (int h = 0; h < 2; h++) {
        int rn = wn + lr;
        boff[h] = (rn * 8 + ((lq + 4 * h) ^ (rn & 7))) * 8;
    }

    f32x4 acc[4];
#pragma unroll
    for (int i = 0; i < 4; i++) acc[i] = (f32x4){0.f, 0.f, 0.f, 0.f};

    for (int k0 = 0; k0 < K; k0 += 64) {
        const unsigned short* Abr = A + (size_t)row0 * K + k0;
        const unsigned short* Bbr = B + (size_t)col0 * K + k0;
        __syncthreads();
#pragma unroll
        for (int q = 0; q < 2; q++)
            GLOAD_LDS16(Abr + (size_t)rowS[q] * K + kclS[q] * 8, &As[slotOff[q]]);
        GLOAD_LDS16(Bbr + (size_t)rowB * K + kclB * 8, &Bs[tid * 8]);
        __syncthreads();
#pragma unroll
        for (int h = 0; h < 2; h++) {
            bf16x8 af[4], bf;
#pragma unroll
            for (int i = 0; i < 4; i++) af[i] = *(const bf16x8*)&As[aoff[i][h]];
            bf = *(const bf16x8*)&Bs[boff[h]];
#pragma unroll
            for (int i = 0; i < 4; i++)
                acc[i] = __builtin_amdgcn_mfma_f32_16x16x32_bf16(af[i], bf,
                                                                 acc[i], 0, 0, 0);
        }
    }
#pragma unroll
    for (int i = 0; i < 4; i++)
#pragma unroll
        for (int r = 0; r < 4; r++) {
            int row = row0 + wm + i * 16 + lq * 4 + r;
            int col = col0 + wn + lr;
            size_t idx = (size_t)row * Dm + col;
            float v = acc[i][r];
            if (bias) v += bias[col];
            C[idx] = C[idx] + v;
        }
}

// ---------------------------------------------------------------------------
// MEGA2: serial scan-chain blocks INTERLEAVED with W4-GEMM thin tiles.
//   mode 0 (320 blks): bid%5==0 = scan group (64 x 4 chunks), else W4 0..255
//   mode 1 (264 blks): bid%33==0 = carry b (8), else W4 tile 256..511
//   mode 2 (768 blks): bid%3==0 = fixup (256), else W4 tile 512..1023
// R11 MEASUREMENT: serial step cost ~0.5 us STANDALONE (2 barriers + LDS RTT)
// — co-scheduling was never the limiter (R7/R9/R10 nulls explained). R12:
// mode-0 scan restructured to ONE barrier/step: 4 chunks/block, full 128-FMA
// dot per thread (arow[128], R3-verified body), double-buffered LDS h state.
// R6 RACE LESSON: W3 GEMM RMWs all of seq -> own launch, never with W4.
// R8 LESSON: carry/fixup bodies byte-identical to R9.
// ---------------------------------------------------------------------------
__global__ __launch_bounds__(512) void mega2(
    int mode,
    const unsigned short* __restrict__ nbuf,
    const unsigned short* __restrict__ W4,
    float* __restrict__ seq,
    const float* __restrict__ boeff,
    const float* __restrict__ ub,
    float* __restrict__ hs,
    unsigned short* __restrict__ hs_bf,
    const float* __restrict__ PowL,
    float* __restrict__ carryb) {
    __shared__ __align__(16) char smem[33280];
    int tid = threadIdx.x;
    int bid = blockIdx.x;

    // role decode (interleaved)
    bool isSerial;
    int sid, gflat;
    if (mode == 0)      { int q = bid / 5, r = bid % 5;
                          isSerial = (r == 0); sid = q; gflat = q * 4 + (r - 1); }
    else if (mode == 1) { int q = bid / 33, r = bid % 33;
                          isSerial = (r == 0); sid = q; gflat = 256 + q * 32 + r - 1; }
    else                { int q = bid / 3, r = bid % 3;
                          isSerial = (r == 0); sid = q; gflat = 512 + q * 2 + (r - 1); }

    if (!isSerial) {
        unsigned short* As = (unsigned short*)smem;            // 16 KB
        unsigned short* Bs = (unsigned short*)(smem + 16384);  //  8 KB
        gemm64_body(gflat, As, Bs, nbuf, W4, seq, boeff, Dm);
        return;
    }

    __builtin_amdgcn_s_setprio(1);

    if (mode == 0) {
        // ---- chunk-local scan, 1 barrier/step: 4 chunks x 128 states ----
        float* bufA = (float*)smem;          // 4 x 128
        float* bufB = bufA + 512;            // 4 x 128
        int cc = tid >> 7, s = tid & 127;
        int chunk = sid * 4 + cc;            // 0..255
        int b = chunk >> 5, c = chunk & 31;  // NCHUNK=32
        const float* Abar = PowL + (size_t)Sn * Sn;   // A^1
        float arow[Sn];
#pragma unroll
        for (int k = 0; k < Sn; k += 4) {
            float4 v = *(const float4*)(Abar + (size_t)s * Sn + k);
            arow[k] = v.x; arow[k + 1] = v.y; arow[k + 2] = v.z; arow[k + 3] = v.w;
        }
        bufA[cc * 128 + s] = 0.f;
        __syncthreads();
        size_t base = (size_t)(b * Lseq + c * Qc) * Sn + s;
        float ut = ub[base];
        float* cur = bufA;
        float* nxt = bufB;
        for (int t = 0; t < Qc; t++) {
            float utn = (t + 1 < Qc) ? ub[base + (size_t)(t + 1) * Sn] : 0.f;
            const float* hch = cur + cc * 128;
            float a0 = 0.f, a1 = 0.f, a2 = 0.f, a3 = 0.f;
#pragma unroll
            for (int k = 0; k < Sn; k += 16) {
                float4 h0 = *(const float4*)&hch[k];
                float4 h1 = *(const float4*)&hch[k + 4];
                float4 h2 = *(const float4*)&hch[k + 8];
                float4 h3 = *(const float4*)&hch[k + 12];
                a0 += arow[k + 0] * h0.x + arow[k + 1] * h0.y + arow[k + 2] * h0.z + arow[k + 3] * h0.w;
                a1 += arow[k + 4] * h1.x + arow[k + 5] * h1.y + arow[k + 6] * h1.z + arow[k + 7] * h1.w;
                a2 += arow[k + 8] * h2.x + arow[k + 9] * h2.y + arow[k + 10] * h2.z + arow[k + 11] * h2.w;
                a3 += arow[k + 12] * h3.x + arow[k + 13] * h3.y + arow[k + 14] * h3.z + arow[k + 15] * h3.w;
            }
            float hv = ut + (a0 + a1) + (a2 + a3);
            hs[base + (size_t)t * Sn] = hv;
            nxt[cc * 128 + s] = hv;
            __syncthreads();             // step t writes done; step t+1 may overwrite cur
            float* tmp = cur; cur = nxt; nxt = tmp;
            ut = utn;
        }
    } else if (mode == 1) {
        // ---- cross-chunk carry scan (k-quarter split, prefetch-1 ends) [R9] ----
        float* csh = (float*)smem;          // 128
        float* cp  = csh + 128;             // 4 x 128
        int b = sid;                        // 0..7
        int s = tid & 127, kq = tid >> 7;
        const float* AQ = PowL + (size_t)Qc * Sn * Sn;   // A^32
        float arow[32];
#pragma unroll
        for (int j = 0; j < 32; j += 4) {
            float4 v = *(const float4*)(AQ + (size_t)s * Sn + kq * 32 + j);
            arow[j] = v.x; arow[j + 1] = v.y; arow[j + 2] = v.z; arow[j + 3] = v.w;
        }
        if (tid < 128) csh[tid] = 0.f;
        __syncthreads();
        float len = (kq == 0) ? hs[(size_t)(b * Lseq + Qc - 1) * Sn + s] : 0.f;
        const float* cq = &csh[kq * 32];
        for (int c = 0; c < NCHUNK; c++) {
            float le_c = len;
            len = (kq == 0 && c + 1 < NCHUNK)
                    ? hs[(size_t)(b * Lseq + (c + 1) * Qc + Qc - 1) * Sn + s] : 0.f;
            if (kq == 0) carryb[((size_t)b * NCHUNK + c) * Sn + s] = csh[s];
            float a0 = 0.f, a1 = 0.f, a2 = 0.f, a3 = 0.f;
#pragma unroll
            for (int j = 0; j < 32; j += 16) {
                float4 h0 = *(const float4*)&cq[j];
                float4 h1 = *(const float4*)&cq[j + 4];
                float4 h2 = *(const float4*)&cq[j + 8];
                float4 h3 = *(const float4*)&cq[j + 12];
                a0 += arow[j + 0] * h0.x + arow[j + 1] * h0.y + arow[j + 2] * h0.z + arow[j + 3] * h0.w;
                a1 += arow[j + 4] * h1.x + arow[j + 5] * h1.y + arow[j + 6] * h1.z + arow[j + 7] * h1.w;
                a2 += arow[j + 8] * h2.x + arow[j + 9] * h2.y + arow[j + 10] * h2.z + arow[j + 11] * h2.w;
                a3 += arow[j + 12] * h3.x + arow[j + 13] * h3.y + arow[j + 14] * h3.z + arow[j + 15] * h3.w;
            }
            cp[kq * 128 + s] = (a0 + a1) + (a2 + a3);
            __syncthreads();
            if (kq == 0)
                csh[s] = le_c + (cp[s] + cp[128 + s]) + (cp[256 + s] + cp[384 + s]);
            __syncthreads();
        }
    } else {
        // ---- fixup: hs_bf = bf16(hs + A^(t+1) @ carry_in), P in 32-quarters [R9] ----
        float* Pl = (float*)smem;                     // 128 x 33 = 16896 B
        float* cl = (float*)(smem + 16896);           // 4 x 1024  = 16384 B
        int t = sid & 31, c4 = sid >> 5;
        const float* P = PowL + (size_t)(t + 1) * (Sn * Sn);
#pragma unroll
        for (int cc = 0; cc < 4; cc++)
            for (int idx = tid; idx < Bn * Sn; idx += 512)
                cl[cc * 1024 + idx] =
                    carryb[((size_t)(idx >> 7) * NCHUNK + (c4 * 4 + cc)) * Sn + (idx & 127)];
        int s = tid & 127, bh = tid >> 7;              // bh 0..3
        float acc[4][2];
#pragma unroll
        for (int cc = 0; cc < 4; cc++) { acc[cc][0] = 0.f; acc[cc][1] = 0.f; }
        for (int kh = 0; kh < 4; kh++) {
            __syncthreads();
            for (int idx = tid; idx < Sn * 32; idx += 512) {
                int r = idx >> 5, kk = idx & 31;
                Pl[r * 33 + kk] = P[(size_t)r * Sn + kh * 32 + kk];
            }
            __syncthreads();
            for (int kk = 0; kk < 32; kk++) {
                float pw = Pl[s * 33 + kk];
                int kg = kh * 32 + kk;
#pragma unroll
                for (int cc = 0; cc < 4; cc++)
#pragma unroll
                    for (int j = 0; j < 2; j++)
                        acc[cc][j] += pw * cl[cc * 1024 + (bh * 2 + j) * Sn + kg];
            }
        }
#pragma unroll
        for (int cc = 0; cc < 4; cc++) {
            int c = c4 * 4 + cc;
#pragma unroll
            for (int j = 0; j < 2; j++) {
                int bb = bh * 2 + j;
                size_t rowi = (size_t)(bb * Lseq + c * Qc + t) * Sn + s;
                hs_bf[rowi] = f2bf(hs[rowi] + acc[cc][j]);
            }
        }
    }
    __builtin_amdgcn_s_setprio(0);
}

// ---------------------------------------------------------------------------
// seq += hs_bf @ W3^T (K=128). OWN launch (RMW-disjointness with W4 tiles).
// ---------------------------------------------------------------------------
__global__ __launch_bounds__(512) void gemm_w3k(const unsigned short* __restrict__ hs_bf,
                                                const unsigned short* __restrict__ W3,
                                                float* __restrict__ seq) {
    __shared__ __align__(16) unsigned short As[1024 * 8]; // 16 KB
    __shared__ __align__(16) unsigned short Bs[512 * 8];  //  8 KB
    gemm64_body(blockIdx.x, As, Bs, hs_bf, W3, seq, nullptr, Sn);
}

// ---------------------------------------------------------------------------
// 128x128 NT GEMM body (bf16 out, z-batched precompute)
// ---------------------------------------------------------------------------
__device__ __forceinline__ void gemm128_body(
    int flat, int ny,
    const unsigned short* __restrict__ A, int sA,
    const unsigned short* __restrict__ Bz, int sB,
    unsigned short* __restrict__ C, int N, int K, float scale,
    unsigned short* As, unsigned short* Bs) {
    int rb = flat % ny, cb = flat / ny;
    int row0 = rb * 128, col0 = cb * 128;
    int tid  = threadIdx.x;
    int wave = tid >> 6, lane = tid & 63;
    int wm = (wave & 1) * 64, wn = (wave >> 1) * 32;
    int lr = lane & 15, lq = lane >> 4;

    int rowS[2], kclS[2], slotOff[2];
#pragma unroll
    for (int q = 0; q < 2; q++) {
        int s = tid + q * 512;
        rowS[q] = s >> 3;
        kclS[q] = (s & 7) ^ ((s >> 3) & 7);
        slotOff[q] = s * 8;
    }
    int aoff[4][2], boff[2][2];
#pragma unroll
    for (int i = 0; i < 4; i++)
#pragma unroll
        for (int h = 0; h < 2; h++) {
            int ra = wm + i * 16 + lr;
            aoff[i][h] = (ra * 8 + ((lq + 4 * h) ^ (ra & 7))) * 8;
        }
#pragma unroll
    for (int j = 0; j < 2; j++)
#pragma unroll
        for (int h = 0; h < 2; h++) {
            int rn = wn + j * 16 + lr;
            boff[j][h] = (rn * 8 + ((lq + 4 * h) ^ (rn & 7))) * 8;
        }

    const unsigned short* Bb = Bz + (size_t)col0 * sB;

    f32x4 acc[4][2];
#pragma unroll
    for (int i = 0; i < 4; i++)
#pragma unroll
        for (int j = 0; j < 2; j++) acc[i][j] = (f32x4){0.f, 0.f, 0.f, 0.f};

    for (int k0 = 0; k0 < K; k0 += 64) {
        const unsigned short* Abr = A + (size_t)row0 * sA + k0;
        const unsigned short* Bbr = Bb + k0;
        __syncthreads();
#pragma unroll
        for (int q = 0; q < 2; q++) {
            GLOAD_LDS16(Abr + (size_t)rowS[q] * sA + kclS[q] * 8, &As[slotOff[q]]);
            GLOAD_LDS16(Bbr + (size_t)rowS[q] * sB + kclS[q] * 8, &Bs[slotOff[q]]);
        }
        __syncthreads();
#pragma unroll
        for (int h = 0; h < 2; h++) {
            bf16x8 af[4], bfr[2];
#pragma unroll
            for (int i = 0; i < 4; i++) af[i]  = *(const bf16x8*)&As[aoff[i][h]];
#pragma unroll
            for (int j = 0; j < 2; j++) bfr[j] = *(const bf16x8*)&Bs[boff[j][h]];
#pragma unroll
            for (int i = 0; i < 4; i++)
#pragma unroll
                for (int j = 0; j < 2; j++)
                    acc[i][j] = __builtin_amdgcn_mfma_f32_16x16x32_bf16(af[i], bfr[j],
                                                                       acc[i][j], 0, 0, 0);
        }
    }
#pragma unroll
    for (int i = 0; i < 4; i++)
#pragma unroll
        for (int j = 0; j < 2; j++)
#pragma unroll
            for (int r = 0; r < 4; r++) {
                int row = row0 + wm + i * 16 + lq * 4 + r;
                int col = col0 + wn + j * 16 + lr;
                C[(size_t)row * N + col] = f2bf(acc[i][j][r] * scale);
            }
}

// Consolidated precompute GEMMs in one launch (320 blocks):
//   [0,32):    M2h[z] = bf16(DT * Bph[z] @ WiTh[z]^T)  z=bid/8, flat=bid%8, ny=1
//   [32,64):   W3h[z] = bf16(Woh[z] @ CpTh[z]^T)       ny=8
//   [64,320):  W4h[z] = bf16(Wo2h[z] @ WiTh[z]^T)      z=(bid-64)/64, ny=8
__global__ __launch_bounds__(512) void gemm_pre(
    const unsigned short* __restrict__ Bph,
    const unsigned short* __restrict__ WiTh,
    unsigned short* __restrict__ M2h,
    const unsigned short* __restrict__ Woh,
    const unsigned short* __restrict__ CpTh,
    unsigned short* __restrict__ W3h,
    const unsigned short* __restrict__ Wo2h,
    unsigned short* __restrict__ W4h) {
    __shared__ __align__(16) unsigned short As[1024 * 8];
    __shared__ __align__(16) unsigned short Bs[1024 * 8];
    const long WW = (long)Dm * Dm;
    const long SW = (long)Sn * Dm;
    int bid = blockIdx.x;
    if (bid < 32) {
        int z = bid >> 3, flat = bid & 7;
        gemm128_body(flat, 1, Bph + (size_t)z * SW, Dm, WiTh + (size_t)z * WW, Dm,
                     M2h + (size_t)z * SW, Dm, Dm, DT_STEP, As, Bs);
    } else if (bid < 64) {
        int b2 = bid - 32;
        int z = b2 >> 3, flat = b2 & 7;
        gemm128_body(flat, 8, Woh + (size_t)z * WW, Dm, CpTh + (size_t)z * SW, Dm,
                     W3h + (size_t)z * SW, Sn, Dm, 1.f, As, Bs);
    } else {
        int b3 = bid - 64;
        int z = b3 >> 6, flat = b3 & 63;
        gemm128_body(flat, 8, Wo2h + (size_t)z * WW, Dm, WiTh + (size_t)z * WW, Dm,
                     W4h + (size_t)z * WW, Dm, Dm, 1.f, As, Bs);
    }
}

// ---------------------------------------------------------------------------
// Matrix powers of A_bar = I + DT*A (fp32 — bf16 would erase the DT*A part!)
// ---------------------------------------------------------------------------
__global__ __launch_bounds__(128) void pow_init(const float* __restrict__ Amat,
                                                float* __restrict__ Pow) {
    int i = blockIdx.x;   // layer
    int s = blockIdx.y;   // row
    int k = threadIdx.x;  // col
    float eye = (s == k) ? 1.f : 0.f;
    size_t base = (size_t)i * NPOW * (Sn * Sn);
    Pow[base + (size_t)s * Sn + k] = eye;  // A^0 = I
    Pow[base + (size_t)(Sn * Sn) + (size_t)s * Sn + k] =
        eye + DT_STEP * Amat[(size_t)i * Sn * Sn + (size_t)s * Sn + k];
}

// Pc = Pa @ Pb, each 128x128 fp32. Block computes 64x32 quadrant.
__global__ __launch_bounds__(256) void pow_mul(float* __restrict__ Pow, int m, int kmax) {
    int job = blockIdx.z;
    int i  = job / kmax;
    int kk = job % kmax + 1;
    const float* Pa = Pow + ((size_t)i * NPOW + m) * (Sn * Sn);
    const float* Pb = Pow + ((size_t)i * NPOW + kk) * (Sn * Sn);
    float*       Pc = Pow + ((size_t)i * NPOW + m + kk) * (Sn * Sn);
    int r0 = blockIdx.y * 64, c0 = blockIdx.x * 32;
    __shared__ float Asl[64 * 129];
    __shared__ float Bsl[128 * 32];
    int tx = threadIdx.x, ty = threadIdx.y;
    int tid = ty * 16 + tx;
    for (int idx = tid; idx < 64 * 128; idx += 256) {
        int r = idx >> 7, cc = idx & 127;
        Asl[r * 129 + cc] = Pa[(size_t)(r0 + r) * 128 + cc];
    }
    for (int idx = tid; idx < 128 * 32; idx += 256) {
        int r = idx >> 5, cc = idx & 31;
        Bsl[r * 32 + cc] = Pb[(size_t)r * 128 + c0 + cc];
    }
    __syncthreads();
    float acc[4][2] = {{0.f,0.f},{0.f,0.f},{0.f,0.f},{0.f,0.f}};
    for (int k = 0; k < 128; k++) {
        float b0 = Bsl[k * 32 + tx * 2];
        float b1 = Bsl[k * 32 + tx * 2 + 1];
#pragma unroll
        for (int r = 0; r < 4; r++) {
            float a = Asl[(ty * 4 + r) * 129 + k];
            acc[r][0] += a * b0;
            acc[r][1] += a * b1;
        }
    }
#pragma unroll
    for (int r = 0; r < 4; r++) {
        Pc[(size_t)(r0 + ty * 4 + r) * 128 + c0 + tx * 2]     = acc[r][0];
        Pc[(size_t)(r0 + ty * 4 + r) * 128 + c0 + tx * 2 + 1] = acc[r][1];
    }
}

// ---------------------------------------------------------------------------
extern "C" void kernel_launch(void* const* d_in, const int* in_sizes, int n_in,
                              void* d_out, int out_size, void* d_ws, size_t ws_size,
                              hipStream_t stream) {
    const float* x     = (const float*)d_in[0];
    const float* Am    = (const float*)d_in[1];
    const float* Bp    = (const float*)d_in[2];
    const float* Cp    = (const float*)d_in[3];
    const float* Dp    = (const float*)d_in[4];
    const float* Wi    = (const float*)d_in[5];
    const float* bi    = (const float*)d_in[6];
    const float* Wo    = (const float*)d_in[7];
    const float* bo    = (const float*)d_in[8];
    const float* gamma = (const float*)d_in[9];
    const float* beta  = (const float*)d_in[10];
    float* out = (float*)d_out;
    (void)in_sizes; (void)n_in; (void)out_size; (void)ws_size;

    // Workspace layout (~107.4 MB)
    char* ws = (char*)d_ws;
    float*          seq   = (float*)(ws + (size_t)0);                 // 32 MB
    unsigned short* nbuf  = (unsigned short*)(ws + (size_t)33554432); // 16 MB
    // precompute-phase aliases inside nbuf region (dead before first ln_ub):
    unsigned short* WiTh  = (unsigned short*)(ws + (size_t)33554432); //  8 MB
    unsigned short* Woh   = (unsigned short*)(ws + (size_t)41943040); //  8 MB
    unsigned short* W4h   = (unsigned short*)(ws + (size_t)50331648); //  8 MB (Wo2@Wi)
    float*          boeff = (float*)(ws + (size_t)58720256);          // 16 KB
    float*          ub    = (float*)(ws + (size_t)67108864);          //  4 MB
    float*          hs    = (float*)(ws + (size_t)71303168);          //  4 MB
    unsigned short* hs_bf = (unsigned short*)(ws + (size_t)75497472); //  2 MB
    float*          Pow   = (float*)(ws + (size_t)77594624);          //  8.25 MB (33 powers)
    float*          carry = (float*)(ws + (size_t)86245376);          //  128 KB
    unsigned short* Wo2h  = (unsigned short*)(ws + (size_t)94765056); //  8 MB (Wo*Dp)
    unsigned short* Bph   = (unsigned short*)(ws + (size_t)103153664);//  1 MB
    unsigned short* CpTh  = (unsigned short*)(ws + (size_t)104202240);//  1 MB
    unsigned short* M2h   = (unsigned short*)(ws + (size_t)105250816);//  1 MB (DT*Bp@Wi)
    unsigned short* W3h   = (unsigned short*)(ws + (size_t)106299392);//  1 MB (Wo@Cp)
    float*          c2dt  = (float*)(ws + (size_t)107347968);         //  2 KB

    const long SW = (long)Sn * Dm;     // 128K

    // ---- precompute: converts + dot products (one launch) ----
    hipLaunchKernelGGL(prep_conv, dim3(2304, DEPTH), dim3(256), 0, stream,
                       Wo, Dp, Bp, bi, bo, Woh, Wo2h, Bph, c2dt, boeff);
    // transposes for Wi and Cp (one launch)
    hipLaunchKernelGGL(transpose_pre, dim3(36, 32, DEPTH), dim3(256), 0, stream,
                       Wi, WiTh, Cp, CpTh);

    // ---- precompute GEMMs: ONE launch, 320 blocks ----
    hipLaunchKernelGGL(gemm_pre, dim3(320), dim3(512), 0, stream,
                       Bph, WiTh, M2h, Woh, CpTh, W3h, Wo2h, W4h);

    // x (B,C,HW) -> seq (B,HW,C)
    hipLaunchKernelGGL(transpose_bll, dim3(32, 32, Bn), dim3(32, 32), 0, stream, x, seq);

    // Matrix powers of A_bar for all layers: I, A^1, then log-doubling to A^32
    hipLaunchKernelGGL(pow_init, dim3(DEPTH, Sn), dim3(Sn), 0, stream, Am, Pow);
    for (int m = 1; m < Qc; m <<= 1) {
        hipLaunchKernelGGL(pow_mul, dim3(4, 2, DEPTH * m), dim3(16, 16), 0, stream,
                           Pow, m, m);
    }

    for (int i = 0; i < DEPTH; i++) {
        const unsigned short* M2_i = M2h + (size_t)i * SW;
        const unsigned short* W3_i = W3h + (size_t)i * SW;
        const unsigned short* W4_i = W4h + (size_t)i * (size_t)(Dm * Dm);
        const float* PowL = Pow + (size_t)i * NPOW * (Sn * Sn);

        // LN + ub-GEMM fused (256 blocks)
        hipLaunchKernelGGL(ln_ub, dim3(256), dim3(512), 0, stream,
                           seq, nbuf, M2_i, ub, gamma + i * Dm, beta + i * Dm,
                           c2dt + i * Sn);
        // scan (64 groups x 4 chunks, 1 barrier/step) + W4 tiles 0..255
        hipLaunchKernelGGL(mega2, dim3(320), dim3(512), 0, stream,
                           0, nbuf, W4_i, seq, boeff + i * Dm,
                           ub, hs, hs_bf, PowL, carry);
        // carry(8) interleaved with W4 tiles 256..511
        hipLaunchKernelGGL(mega2, dim3(264), dim3(512), 0, stream,
                           1, nbuf, W4_i, seq, boeff + i * Dm,
                           ub, hs, hs_bf, PowL, carry);
        // fixup(256) interleaved with W4 tiles 512..1023
        hipLaunchKernelGGL(mega2, dim3(768), dim3(512), 0, stream,
                           2, nbuf, W4_i, seq, boeff + i * Dm,
                           ub, hs, hs_bf, PowL, carry);
        // seq += hs_bf @ W3^T (K=128) — own launch (RMW-disjointness with W4)
        hipLaunchKernelGGL(gemm_w3k, dim3(1024), dim3(512), 0, stream,
                           hs_bf, W3_i, seq);
    }

    // seq (B,HW,C) -> out (B,C,HW)
    hipLaunchKernelGGL(transpose_bll, dim3(32, 32, Bn), dim3(32, 32), 0, stream, seq, out);
}

// Round 14
// 705.222 us; speedup vs baseline: 1.2450x; 1.2450x over previous
//
#include <hip/hip_runtime.h>
#include <stdint.h>

// Problem constants (MambaBlock: B=8, C=d=1024, H*W=L=1024, depth=4, S=128)
#define DT_STEP 0.001f
#define LN_EPS  1e-5f
#define Bn      8
#define Lseq    1024
#define Dm      1024
#define Sn      128
#define DEPTH   4
#define Mrows   (Bn * Lseq)       // 8192
#define Qc      32                // scan chunk size
#define NCHUNK  (Lseq / Qc)       // 32
#define NPOW    33                // powers 0..32 per layer

typedef short bf16x8 __attribute__((ext_vector_type(8)));
typedef float f32x4  __attribute__((ext_vector_type(4)));

__device__ __forceinline__ unsigned short f2bf(float f) {
    unsigned int u = __float_as_uint(f);
    u += 0x7fffu + ((u >> 16) & 1u);          // round-to-nearest-even
    return (unsigned short)(u >> 16);
}

// async 16B global->LDS (wave-uniform LDS base + lane*16; slot linear in lane)
#define GLOAD_LDS16(gp, lp)                                                \
    __builtin_amdgcn_global_load_lds(                                      \
        (const __attribute__((address_space(1))) unsigned int*)(gp),       \
        (__attribute__((address_space(3))) unsigned int*)(lp), 16, 0, 0)

// ---------------------------------------------------------------------------
// Merged precompute: converts + small dot products.
//   bx < 1024        : Woh = bf16(Wo), Wo2h = bf16(Wo*Dp)
//   1024 <= bx <1152 : Bph = bf16(Bp)
//   bx >= 1152       : j = bx-1152;
//       j <  Sn : c2dt[z,j]  = DT * sum_k Bp[z,j,k]*bi[z,k]
//       j >= Sn : boeff[z,c] = bo[z,c] + sum_k Wo[z,c,k]*Dp[z,k]*bi[z,k]
// grid (2304, DEPTH) x 256
// ---------------------------------------------------------------------------
__global__ __launch_bounds__(256) void prep_conv(const float* __restrict__ Wo,
                                                 const float* __restrict__ Dp,
                                                 const float* __restrict__ Bp,
                                                 const float* __restrict__ bi,
                                                 const float* __restrict__ bo,
                                                 unsigned short* __restrict__ Woh,
                                                 unsigned short* __restrict__ Wo2h,
                                                 unsigned short* __restrict__ Bph,
                                                 float* __restrict__ c2dt,
                                                 float* __restrict__ boeff) {
    int z = blockIdx.y;
    int bx = blockIdx.x;
    int tid = threadIdx.x;
    if (bx < 1024) {
        int i = (bx * 256 + tid) * 4;                   // within z's 1M elems
        const float* S = Wo + (size_t)z * Dm * Dm;
        float4 v = *(const float4*)(S + i);
        int c = i & (Dm - 1);
        float4 d = *(const float4*)(Dp + (size_t)z * Dm + c);
        ushort4 o1, o2;
        o1.x = f2bf(v.x); o1.y = f2bf(v.y); o1.z = f2bf(v.z); o1.w = f2bf(v.w);
        o2.x = f2bf(v.x * d.x); o2.y = f2bf(v.y * d.y);
        o2.z = f2bf(v.z * d.z); o2.w = f2bf(v.w * d.w);
        *(ushort4*)(Woh  + (size_t)z * Dm * Dm + i) = o1;
        *(ushort4*)(Wo2h + (size_t)z * Dm * Dm + i) = o2;
        return;
    } else if (bx < 1152) {
        int i = ((bx - 1024) * 256 + tid) * 4;          // 128 blks * 1024 = Sn*Dm
        float4 v = *(const float4*)(Bp + (size_t)z * Sn * Dm + i);
        ushort4 o;
        o.x = f2bf(v.x); o.y = f2bf(v.y); o.z = f2bf(v.z); o.w = f2bf(v.w);
        *(ushort4*)(Bph + (size_t)z * Sn * Dm + i) = o;
        return;
    }
    // dot-product section
    int j = bx - 1152;
    float acc;
    if (j < Sn) {
        const float* br = Bp + ((size_t)z * Sn + j) * Dm;
        const float* bb = bi + (size_t)z * Dm;
        float4 v = *(const float4*)(br + tid * 4);
        float4 w = *(const float4*)(bb + tid * 4);
        acc = v.x * w.x + v.y * w.y + v.z * w.z + v.w * w.w;
    } else {
        int c = j - Sn;
        const float* wr = Wo + ((size_t)z * Dm + c) * Dm;
        const float* dp = Dp + (size_t)z * Dm;
        const float* bb = bi + (size_t)z * Dm;
        float4 w = *(const float4*)(wr + tid * 4);
        float4 d = *(const float4*)(dp + tid * 4);
        float4 b = *(const float4*)(bb + tid * 4);
        acc = w.x * d.x * b.x + w.y * d.y * b.y + w.z * d.z * b.z + w.w * d.w * b.w;
    }
#pragma unroll
    for (int off = 32; off > 0; off >>= 1) acc += __shfl_down(acc, off, 64);
    __shared__ float red[4];
    if ((tid & 63) == 0) red[tid >> 6] = acc;
    __syncthreads();
    if (tid == 0) {
        float tot = red[0] + red[1] + red[2] + red[3];
        if (j < Sn) c2dt[z * Sn + j] = DT_STEP * tot;
        else        boeff[(size_t)z * Dm + (j - Sn)] = bo[(size_t)z * Dm + (j - Sn)] + tot;
    }
}

// ---------------------------------------------------------------------------
// Merged transpose+convert for Wi (1024x1024) and Cp (1024x128), batched z.
// grid (36, 32, DEPTH): bx<32 -> Wi tile; bx>=32 -> Cp tile (bx-32 in 0..3).
// ---------------------------------------------------------------------------
__global__ __launch_bounds__(256) void transpose_pre(const float* __restrict__ Wi,
                                                     unsigned short* __restrict__ WiTh,
                                                     const float* __restrict__ Cp,
                                                     unsigned short* __restrict__ CpTh) {
    __shared__ float t[32][33];
    int z = blockIdx.z;
    const float* S;
    unsigned short* D;
    int R, C, r0, c0;
    if ((int)blockIdx.x < 32) {
        S = Wi + (size_t)z * Dm * Dm;  D = WiTh + (size_t)z * Dm * Dm;
        R = Dm; C = Dm;
        r0 = blockIdx.y * 32; c0 = blockIdx.x * 32;
    } else {
        S = Cp + (size_t)z * Dm * Sn;  D = CpTh + (size_t)z * Dm * Sn;
        R = Dm; C = Sn;
        r0 = blockIdx.y * 32; c0 = (blockIdx.x - 32) * 32;
    }
    int tx = threadIdx.x & 31, ty = threadIdx.x >> 5;   // 32 x 8
    for (int rr = ty; rr < 32; rr += 8)
        t[rr][tx] = S[(size_t)(r0 + rr) * C + c0 + tx];
    __syncthreads();
    for (int rr = ty; rr < 32; rr += 8)
        D[(size_t)(c0 + rr) * R + r0 + tx] = f2bf(t[tx][rr]);
}

// ---------------------------------------------------------------------------
// Batched 1024x1024 transpose fp32: dst[b][i][j] = src[b][j][i]
// ---------------------------------------------------------------------------
__global__ __launch_bounds__(1024) void transpose_bll(const float* __restrict__ src,
                                                      float* __restrict__ dst) {
    __shared__ float tile[32][33];
    int b  = blockIdx.z;
    int i0 = blockIdx.y * 32, j0 = blockIdx.x * 32;
    int tx = threadIdx.x, ty = threadIdx.y;
    const float* S = src + (size_t)b * Dm * Lseq;
    float*       D = dst + (size_t)b * Dm * Lseq;
    tile[ty][tx] = S[(size_t)(j0 + ty) * 1024 + i0 + tx];
    __syncthreads();
    D[(size_t)(i0 + ty) * 1024 + j0 + tx] = tile[tx][ty];
}

// ---------------------------------------------------------------------------
// FUSED LayerNorm + ub-GEMM (verified R5). 256 blocks x 512 thr; 32 rows/block.
// ---------------------------------------------------------------------------
__global__ __launch_bounds__(512) void ln_ub(
    const float* __restrict__ seq,
    unsigned short* __restrict__ nbuf,
    const unsigned short* __restrict__ M2,
    float* __restrict__ ub,
    const float* __restrict__ gam,
    const float* __restrict__ bet,
    const float* __restrict__ c2dtL) {
    __shared__ __align__(16) unsigned short As[256 * 8];   //  4 KB
    __shared__ __align__(16) unsigned short Bs[1024 * 8];  // 16 KB
    __shared__ float mrow[32], rrow[32];
    int row0 = blockIdx.x * 32;
    int tid = threadIdx.x;

    // ---- Phase A: stats, 16 threads per row ----
    {
        int r = tid >> 4, l = tid & 15;
        const float* xr = seq + (size_t)(row0 + r) * Dm + l * 4;
        float s = 0.f, ss = 0.f;
#pragma unroll
        for (int j = 0; j < 16; j++) {
            float4 v = *(const float4*)(xr + j * 64);
            s  += v.x + v.y + v.z + v.w;
            ss += v.x * v.x + v.y * v.y + v.z * v.z + v.w * v.w;
        }
        s += __shfl_xor(s, 1, 16);  ss += __shfl_xor(ss, 1, 16);
        s += __shfl_xor(s, 2, 16);  ss += __shfl_xor(ss, 2, 16);
        s += __shfl_xor(s, 4, 16);  ss += __shfl_xor(ss, 4, 16);
        s += __shfl_xor(s, 8, 16);  ss += __shfl_xor(ss, 8, 16);
        if (l == 0) {
            float mean = s / (float)Dm;
            float var  = ss / (float)Dm - mean * mean;
            mrow[r] = mean;
            rrow[r] = rsqrtf(var + LN_EPS);
        }
    }
    __syncthreads();
    // ---- Phase A2: normalize -> nbuf (coalesced 16B stores)
#pragma unroll
    for (int g = 0; g < 8; g++) {
        int gi = tid + g * 512;              // 0..4095 = 32 rows x 128 granules
        int rA = gi >> 7, gc = gi & 127;
        int col = gc * 8;
        const float* p = seq + (size_t)(row0 + rA) * Dm + col;
        float4 v0 = *(const float4*)(p);
        float4 v1 = *(const float4*)(p + 4);
        float m = mrow[rA], rs = rrow[rA];
        float4 g0 = *(const float4*)(gam + col);
        float4 g1 = *(const float4*)(gam + col + 4);
        float4 b0 = *(const float4*)(bet + col);
        float4 b1 = *(const float4*)(bet + col + 4);
        bf16x8 pk;
        pk[0] = (short)f2bf((v0.x - m) * rs * g0.x + b0.x);
        pk[1] = (short)f2bf((v0.y - m) * rs * g0.y + b0.y);
        pk[2] = (short)f2bf((v0.z - m) * rs * g0.z + b0.z);
        pk[3] = (short)f2bf((v0.w - m) * rs * g0.w + b0.w);
        pk[4] = (short)f2bf((v1.x - m) * rs * g1.x + b1.x);
        pk[5] = (short)f2bf((v1.y - m) * rs * g1.y + b1.y);
        pk[6] = (short)f2bf((v1.z - m) * rs * g1.z + b1.z);
        pk[7] = (short)f2bf((v1.w - m) * rs * g1.w + b1.w);
        *(bf16x8*)(nbuf + (size_t)(row0 + rA) * Dm + col) = pk;
    }
    __syncthreads();   // drains global stores (vmcnt 0) before async reads

    // ---- Phase B: ub-GEMM on own rows ----
    int wave = tid >> 6, lane = tid & 63;
    int wn = wave * 16;
    int lr = lane & 15, lq = lane >> 4;

    int rowA = tid >> 3;                        // 0..31 for tid<256
    int kclA = (tid & 7) ^ ((tid >> 3) & 7);
    int rowS[2], kclS[2], slotOff[2];
#pragma unroll
    for (int q = 0; q < 2; q++) {
        int s = tid + q * 512;
        rowS[q] = s >> 3;
        kclS[q] = (s & 7) ^ ((s >> 3) & 7);
        slotOff[q] = s * 8;
    }
    int aoff[2][2], boff[2];
#pragma unroll
    for (int i = 0; i < 2; i++)
#pragma unroll
        for (int h = 0; h < 2; h++) {
            int ra = i * 16 + lr;
            aoff[i][h] = (ra * 8 + ((lq + 4 * h) ^ (ra & 7))) * 8;
        }
#pragma unroll
    for (int h = 0; h < 2; h++) {
        int rn = wn + lr;
        boff[h] = (rn * 8 + ((lq + 4 * h) ^ (rn & 7))) * 8;
    }

    f32x4 acc[2];
#pragma unroll
    for (int i = 0; i < 2; i++) acc[i] = (f32x4){0.f, 0.f, 0.f, 0.f};

    for (int k0 = 0; k0 < Dm; k0 += 64) {
        const unsigned short* Abr = nbuf + (size_t)row0 * Dm + k0;
        const unsigned short* Bbr = M2 + k0;
        __syncthreads();
        if (tid < 256)
            GLOAD_LDS16(Abr + (size_t)rowA * Dm + kclA * 8, &As[tid * 8]);
#pragma unroll
        for (int q = 0; q < 2; q++)
            GLOAD_LDS16(Bbr + (size_t)rowS[q] * Dm + kclS[q] * 8, &Bs[slotOff[q]]);
        __syncthreads();
#pragma unroll
        for (int h = 0; h < 2; h++) {
            bf16x8 af[2], bfr;
#pragma unroll
            for (int i = 0; i < 2; i++) af[i] = *(const bf16x8*)&As[aoff[i][h]];
            bfr = *(const bf16x8*)&Bs[boff[h]];
#pragma unroll
            for (int i = 0; i < 2; i++)
                acc[i] = __builtin_amdgcn_mfma_f32_16x16x32_bf16(af[i], bfr,
                                                                 acc[i], 0, 0, 0);
        }
    }
#pragma unroll
    for (int i = 0; i < 2; i++)
#pragma unroll
        for (int r = 0; r < 4; r++) {
            int row = row0 + i * 16 + lq * 4 + r;
            int col = wn + lr;
            ub[(size_t)row * Sn + col] = acc[i][r] + c2dtL[col];
        }
}

// ---------------------------------------------------------------------------
// 128x64-tile residual GEMM body: C(8192x1024 fp32) += A @ B^T (+ bias).
// RMW on C: tiles touching the same C elements must NEVER share a launch.
// ---------------------------------------------------------------------------
__device__ __forceinline__ void gemm64_body(
    int flat, unsigned short* As, unsigned short* Bs,
    const unsigned short* __restrict__ A, const unsigned short* __restrict__ B,
    float* __restrict__ C, const float* __restrict__ bias, int K) {
    int rb = flat & 63, cb = flat >> 6;
    int row0 = rb * 128, col0 = cb * 64;
    int tid  = threadIdx.x;
    int wave = tid >> 6, lane = tid & 63;
    int wm = (wave & 1) * 64, wn = (wave >> 1) * 16;
    int lr = lane & 15, lq = lane >> 4;

    int rowS[2], kclS[2], slotOff[2];
#pragma unroll
    for (int q = 0; q < 2; q++) {
        int s = tid + q * 512;
        rowS[q] = s >> 3;
        kclS[q] = (s & 7) ^ ((s >> 3) & 7);
        slotOff[q] = s * 8;
    }
    int rowB = tid >> 3;
    int kclB = (tid & 7) ^ ((tid >> 3) & 7);

    int aoff[4][2], boff[2];
#pragma unroll
    for (int i = 0; i < 4; i++)
#pragma unroll
        for (int h = 0; h < 2; h++) {
            int ra = wm + i * 16 + lr;
            aoff[i][h] = (ra * 8 + ((lq + 4 * h) ^ (ra & 7))) * 8;
        }
#pragma unroll
    for (int h = 0; h < 2; h++) {
        int rn = wn + lr;
        boff[h] = (rn * 8 + ((lq + 4 * h) ^ (rn & 7))) * 8;
    }

    f32x4 acc[4];
#pragma unroll
    for (int i = 0; i < 4; i++) acc[i] = (f32x4){0.f, 0.f, 0.f, 0.f};

    for (int k0 = 0; k0 < K; k0 += 64) {
        const unsigned short* Abr = A + (size_t)row0 * K + k0;
        const unsigned short* Bbr = B + (size_t)col0 * K + k0;
        __syncthreads();
#pragma unroll
        for (int q = 0; q < 2; q++)
            GLOAD_LDS16(Abr + (size_t)rowS[q] * K + kclS[q] * 8, &As[slotOff[q]]);
        GLOAD_LDS16(Bbr + (size_t)rowB * K + kclB * 8, &Bs[tid * 8]);
        __syncthreads();
#pragma unroll
        for (int h = 0; h < 2; h++) {
            bf16x8 af[4], bf;
#pragma unroll
            for (int i = 0; i < 4; i++) af[i] = *(const bf16x8*)&As[aoff[i][h]];
            bf = *(const bf16x8*)&Bs[boff[h]];
#pragma unroll
            for (int i = 0; i < 4; i++)
                acc[i] = __builtin_amdgcn_mfma_f32_16x16x32_bf16(af[i], bf,
                                                                 acc[i], 0, 0, 0);
        }
    }
#pragma unroll
    for (int i = 0; i < 4; i++)
#pragma unroll
        for (int r = 0; r < 4; r++) {
            int row = row0 + wm + i * 16 + lq * 4 + r;
            int col = col0 + wn + lr;
            size_t idx = (size_t)row * Dm + col;
            float v = acc[i][r];
            if (bias) v += bias[col];
            C[idx] = C[idx] + v;
        }
}

// ---------------------------------------------------------------------------
// MEGA2: serial scan-chain blocks INTERLEAVED with W4-GEMM filler tiles.
//   mode 0 (512 blks): even = scan chunk (256), odd = W4 tile 0..255
//   mode 1 (264 blks): bid%33==0 = carry b (8), else W4 tile 256..511
//   mode 2 (768 blks): bid%3==0 = fixup (256), else W4 tile 512..1023
// T5: serial waves run at s_setprio(1); GEMM fillers at 0 (issue-starvation
// theory from R7: scan chain gets ~1/4 issue bandwidth vs co-resident GEMM).
// R6 RACE LESSON: W3 GEMM RMWs all of seq -> own launch, never with W4.
// R8 LESSON: transplanted FMA blocks must be diffed mechanically (h1.z typo).
// R12 LESSON: no arow[128] in this multi-role kernel — VGPR 44->80 spilled
// the scan to scratch AND cut GEMM occupancy (G6: per-thread array budget).
// ---------------------------------------------------------------------------
__global__ __launch_bounds__(512) void mega2(
    int mode,
    const unsigned short* __restrict__ nbuf,
    const unsigned short* __restrict__ W4,
    float* __restrict__ seq,
    const float* __restrict__ boeff,
    const float* __restrict__ ub,
    float* __restrict__ hs,
    unsigned short* __restrict__ hs_bf,
    const float* __restrict__ PowL,
    float* __restrict__ carryb) {
    __shared__ __align__(16) char smem[33280];
    int tid = threadIdx.x;
    int bid = blockIdx.x;

    // role decode (interleaved)
    bool isSerial;
    int sid, gflat;
    if (mode == 0)      { isSerial = (bid & 1) == 0; sid = bid >> 1; gflat = bid >> 1; }
    else if (mode == 1) { int q = bid / 33, r = bid % 33;
                          isSerial = (r == 0); sid = q; gflat = 256 + q * 32 + r - 1; }
    else                { int q = bid / 3, r = bid % 3;
                          isSerial = (r == 0); sid = q; gflat = 512 + q * 2 + (r - 1); }

    if (!isSerial) {
        unsigned short* As = (unsigned short*)smem;            // 16 KB
        unsigned short* Bs = (unsigned short*)(smem + 16384);  //  8 KB
        gemm64_body(gflat, As, Bs, nbuf, W4, seq, boeff, Dm);
        return;
    }

    // latency-critical serial roles: prefer these waves on the CU scheduler
    __builtin_amdgcn_s_setprio(1);

    if (mode == 0) {
        // ---- chunk-local scan: h_t = A_bar @ h_{t-1} + ub_t ----
        float* hsh = (float*)smem;          // 128
        float* hp  = hsh + 128;             // 4 x 128
        int b = sid >> 5, c = sid & 31;
        int s = tid & 127, kq = tid >> 7;
        const float* Abar = PowL + (size_t)Sn * Sn;   // A^1
        float arow[32];
#pragma unroll
        for (int j = 0; j < 32; j += 4) {
            float4 v = *(const float4*)(Abar + (size_t)s * Sn + kq * 32 + j);
            arow[j] = v.x; arow[j + 1] = v.y; arow[j + 2] = v.z; arow[j + 3] = v.w;
        }
        if (tid < 128) hsh[tid] = 0.f;
        __syncthreads();
        size_t base = (size_t)(b * Lseq + c * Qc) * Sn + s;
        float ut = (kq == 0) ? ub[base] : 0.f;
        const float* hq = &hsh[kq * 32];
        for (int t = 0; t < Qc; t++) {
            float utn = (kq == 0 && t + 1 < Qc) ? ub[base + (size_t)(t + 1) * Sn] : 0.f;
            float a0 = 0.f, a1 = 0.f, a2 = 0.f, a3 = 0.f;
#pragma unroll
            for (int j = 0; j < 32; j += 16) {
                float4 h0 = *(const float4*)&hq[j];
                float4 h1 = *(const float4*)&hq[j + 4];
                float4 h2 = *(const float4*)&hq[j + 8];
                float4 h3 = *(const float4*)&hq[j + 12];
                a0 += arow[j + 0] * h0.x + arow[j + 1] * h0.y + arow[j + 2] * h0.z + arow[j + 3] * h0.w;
                a1 += arow[j + 4] * h1.x + arow[j + 5] * h1.y + arow[j + 6] * h1.z + arow[j + 7] * h1.w;
                a2 += arow[j + 8] * h2.x + arow[j + 9] * h2.y + arow[j + 10] * h2.z + arow[j + 11] * h2.w;
                a3 += arow[j + 12] * h3.x + arow[j + 13] * h3.y + arow[j + 14] * h3.z + arow[j + 15] * h3.w;
            }
            hp[kq * 128 + s] = (a0 + a1) + (a2 + a3);
            __syncthreads();
            if (kq == 0) {
                float hv = ut + (hp[s] + hp[128 + s]) + (hp[256 + s] + hp[384 + s]);
                hs[base + (size_t)t * Sn] = hv;
                hsh[s] = hv;
            }
            __syncthreads();
            ut = utn;
        }
    } else if (mode == 1) {
        // ---- cross-chunk carry scan (k-quarter split, prefetch-1 ends) ----
        float* csh = (float*)smem;          // 128
        float* cp  = csh + 128;             // 4 x 128
        int b = sid;                        // 0..7
        int s = tid & 127, kq = tid >> 7;
        const float* AQ = PowL + (size_t)Qc * Sn * Sn;   // A^32
        float arow[32];
#pragma unroll
        for (int j = 0; j < 32; j += 4) {
            float4 v = *(const float4*)(AQ + (size_t)s * Sn + kq * 32 + j);
            arow[j] = v.x; arow[j + 1] = v.y; arow[j + 2] = v.z; arow[j + 3] = v.w;
        }
        if (tid < 128) csh[tid] = 0.f;
        __syncthreads();
        float len = (kq == 0) ? hs[(size_t)(b * Lseq + Qc - 1) * Sn + s] : 0.f;
        const float* cq = &csh[kq * 32];
        for (int c = 0; c < NCHUNK; c++) {
            float le_c = len;
            len = (kq == 0 && c + 1 < NCHUNK)
                    ? hs[(size_t)(b * Lseq + (c + 1) * Qc + Qc - 1) * Sn + s] : 0.f;
            if (kq == 0) carryb[((size_t)b * NCHUNK + c) * Sn + s] = csh[s];
            float a0 = 0.f, a1 = 0.f, a2 = 0.f, a3 = 0.f;
#pragma unroll
            for (int j = 0; j < 32; j += 16) {
                float4 h0 = *(const float4*)&cq[j];
                float4 h1 = *(const float4*)&cq[j + 4];
                float4 h2 = *(const float4*)&cq[j + 8];
                float4 h3 = *(const float4*)&cq[j + 12];
                a0 += arow[j + 0] * h0.x + arow[j + 1] * h0.y + arow[j + 2] * h0.z + arow[j + 3] * h0.w;
                a1 += arow[j + 4] * h1.x + arow[j + 5] * h1.y + arow[j + 6] * h1.z + arow[j + 7] * h1.w;
                a2 += arow[j + 8] * h2.x + arow[j + 9] * h2.y + arow[j + 10] * h2.z + arow[j + 11] * h2.w;
                a3 += arow[j + 12] * h3.x + arow[j + 13] * h3.y + arow[j + 14] * h3.z + arow[j + 15] * h3.w;
            }
            cp[kq * 128 + s] = (a0 + a1) + (a2 + a3);
            __syncthreads();
            if (kq == 0)
                csh[s] = le_c + (cp[s] + cp[128 + s]) + (cp[256 + s] + cp[384 + s]);
            __syncthreads();
        }
    } else {
        // ---- fixup: hs_bf = bf16(hs + A^(t+1) @ carry_in), P in 32-quarters ----
        float* Pl = (float*)smem;                     // 128 x 33 = 16896 B
        float* cl = (float*)(smem + 16896);           // 4 x 1024  = 16384 B
        int t = sid & 31, c4 = sid >> 5;
        const float* P = PowL + (size_t)(t + 1) * (Sn * Sn);
#pragma unroll
        for (int cc = 0; cc < 4; cc++)
            for (int idx = tid; idx < Bn * Sn; idx += 512)
                cl[cc * 1024 + idx] =
                    carryb[((size_t)(idx >> 7) * NCHUNK + (c4 * 4 + cc)) * Sn + (idx & 127)];
        int s = tid & 127, bh = tid >> 7;              // bh 0..3
        float acc[4][2];
#pragma unroll
        for (int cc = 0; cc < 4; cc++) { acc[cc][0] = 0.f; acc[cc][1] = 0.f; }
        for (int kh = 0; kh < 4; kh++) {
            __syncthreads();
            for (int idx = tid; idx < Sn * 32; idx += 512) {
                int r = idx >> 5, kk = idx & 31;
                Pl[r * 33 + kk] = P[(size_t)r * Sn + kh * 32 + kk];
            }
            __syncthreads();
            for (int kk = 0; kk < 32; kk++) {
                float pw = Pl[s * 33 + kk];
                int kg = kh * 32 + kk;
#pragma unroll
                for (int cc = 0; cc < 4; cc++)
#pragma unroll
                    for (int j = 0; j < 2; j++)
                        acc[cc][j] += pw * cl[cc * 1024 + (bh * 2 + j) * Sn + kg];
            }
        }
#pragma unroll
        for (int cc = 0; cc < 4; cc++) {
            int c = c4 * 4 + cc;
#pragma unroll
            for (int j = 0; j < 2; j++) {
                int bb = bh * 2 + j;
                size_t rowi = (size_t)(bb * Lseq + c * Qc + t) * Sn + s;
                hs_bf[rowi] = f2bf(hs[rowi] + acc[cc][j]);
            }
        }
    }
    __builtin_amdgcn_s_setprio(0);
}

// ---------------------------------------------------------------------------
// seq += hs_bf @ W3^T (K=128). OWN launch: it RMWs all of seq, so it must be
// stream-ordered after every W4 tile (R6 race lesson).
// ---------------------------------------------------------------------------
__global__ __launch_bounds__(512) void gemm_w3k(const unsigned short* __restrict__ hs_bf,
                                                const unsigned short* __restrict__ W3,
                                                float* __restrict__ seq) {
    __shared__ __align__(16) unsigned short As[1024 * 8]; // 16 KB
    __shared__ __align__(16) unsigned short Bs[512 * 8];  //  8 KB
    gemm64_body(blockIdx.x, As, Bs, hs_bf, W3, seq, nullptr, Sn);
}

// ---------------------------------------------------------------------------
// 128x128 NT GEMM body (bf16 out, z-batched precompute)
// ---------------------------------------------------------------------------
__device__ __forceinline__ void gemm128_body(
    int flat, int ny,
    const unsigned short* __restrict__ A, int sA,
    const unsigned short* __restrict__ Bz, int sB,
    unsigned short* __restrict__ C, int N, int K, float scale,
    unsigned short* As, unsigned short* Bs) {
    int rb = flat % ny, cb = flat / ny;
    int row0 = rb * 128, col0 = cb * 128;
    int tid  = threadIdx.x;
    int wave = tid >> 6, lane = tid & 63;
    int wm = (wave & 1) * 64, wn = (wave >> 1) * 32;
    int lr = lane & 15, lq = lane >> 4;

    int rowS[2], kclS[2], slotOff[2];
#pragma unroll
    for (int q = 0; q < 2; q++) {
        int s = tid + q * 512;
        rowS[q] = s >> 3;
        kclS[q] = (s & 7) ^ ((s >> 3) & 7);
        slotOff[q] = s * 8;
    }
    int aoff[4][2], boff[2][2];
#pragma unroll
    for (int i = 0; i < 4; i++)
#pragma unroll
        for (int h = 0; h < 2; h++) {
            int ra = wm + i * 16 + lr;
            aoff[i][h] = (ra * 8 + ((lq + 4 * h) ^ (ra & 7))) * 8;
        }
#pragma unroll
    for (int j = 0; j < 2; j++)
#pragma unroll
        for (int h = 0; h < 2; h++) {
            int rn = wn + j * 16 + lr;
            boff[j][h] = (rn * 8 + ((lq + 4 * h) ^ (rn & 7))) * 8;
        }

    const unsigned short* Bb = Bz + (size_t)col0 * sB;

    f32x4 acc[4][2];
#pragma unroll
    for (int i = 0; i < 4; i++)
#pragma unroll
        for (int j = 0; j < 2; j++) acc[i][j] = (f32x4){0.f, 0.f, 0.f, 0.f};

    for (int k0 = 0; k0 < K; k0 += 64) {
        const unsigned short* Abr = A + (size_t)row0 * sA + k0;
        const unsigned short* Bbr = Bb + k0;
        __syncthreads();
#pragma unroll
        for (int q = 0; q < 2; q++) {
            GLOAD_LDS16(Abr + (size_t)rowS[q] * sA + kclS[q] * 8, &As[slotOff[q]]);
            GLOAD_LDS16(Bbr + (size_t)rowS[q] * sB + kclS[q] * 8, &Bs[slotOff[q]]);
        }
        __syncthreads();
#pragma unroll
        for (int h = 0; h < 2; h++) {
            bf16x8 af[4], bfr[2];
#pragma unroll
            for (int i = 0; i < 4; i++) af[i]  = *(const bf16x8*)&As[aoff[i][h]];
#pragma unroll
            for (int j = 0; j < 2; j++) bfr[j] = *(const bf16x8*)&Bs[boff[j][h]];
#pragma unroll
            for (int i = 0; i < 4; i++)
#pragma unroll
                for (int j = 0; j < 2; j++)
                    acc[i][j] = __builtin_amdgcn_mfma_f32_16x16x32_bf16(af[i], bfr[j],
                                                                       acc[i][j], 0, 0, 0);
        }
    }
#pragma unroll
    for (int i = 0; i < 4; i++)
#pragma unroll
        for (int j = 0; j < 2; j++)
#pragma unroll
            for (int r = 0; r < 4; r++) {
                int row = row0 + wm + i * 16 + lq * 4 + r;
                int col = col0 + wn + j * 16 + lr;
                C[(size_t)row * N + col] = f2bf(acc[i][j][r] * scale);
            }
}

// Consolidated precompute GEMMs in one launch (320 blocks):
//   [0,32):    M2h[z] = bf16(DT * Bph[z] @ WiTh[z]^T)  z=bid/8, flat=bid%8, ny=1
//   [32,64):   W3h[z] = bf16(Woh[z] @ CpTh[z]^T)       ny=8
//   [64,320):  W4h[z] = bf16(Wo2h[z] @ WiTh[z]^T)      z=(bid-64)/64, ny=8
__global__ __launch_bounds__(512) void gemm_pre(
    const unsigned short* __restrict__ Bph,
    const unsigned short* __restrict__ WiTh,
    unsigned short* __restrict__ M2h,
    const unsigned short* __restrict__ Woh,
    const unsigned short* __restrict__ CpTh,
    unsigned short* __restrict__ W3h,
    const unsigned short* __restrict__ Wo2h,
    unsigned short* __restrict__ W4h) {
    __shared__ __align__(16) unsigned short As[1024 * 8];
    __shared__ __align__(16) unsigned short Bs[1024 * 8];
    const long WW = (long)Dm * Dm;
    const long SW = (long)Sn * Dm;
    int bid = blockIdx.x;
    if (bid < 32) {
        int z = bid >> 3, flat = bid & 7;
        gemm128_body(flat, 1, Bph + (size_t)z * SW, Dm, WiTh + (size_t)z * WW, Dm,
                     M2h + (size_t)z * SW, Dm, Dm, DT_STEP, As, Bs);
    } else if (bid < 64) {
        int b2 = bid - 32;
        int z = b2 >> 3, flat = b2 & 7;
        gemm128_body(flat, 8, Woh + (size_t)z * WW, Dm, CpTh + (size_t)z * SW, Dm,
                     W3h + (size_t)z * SW, Sn, Dm, 1.f, As, Bs);
    } else {
        int b3 = bid - 64;
        int z = b3 >> 6, flat = b3 & 63;
        gemm128_body(flat, 8, Wo2h + (size_t)z * WW, Dm, WiTh + (size_t)z * WW, Dm,
                     W4h + (size_t)z * WW, Dm, Dm, 1.f, As, Bs);
    }
}

// ---------------------------------------------------------------------------
// Matrix powers of A_bar = I + DT*A (fp32 — bf16 would erase the DT*A part!)
// ---------------------------------------------------------------------------
__global__ __launch_bounds__(128) void pow_init(const float* __restrict__ Amat,
                                                float* __restrict__ Pow) {
    int i = blockIdx.x;   // layer
    int s = blockIdx.y;   // row
    int k = threadIdx.x;  // col
    float eye = (s == k) ? 1.f : 0.f;
    size_t base = (size_t)i * NPOW * (Sn * Sn);
    Pow[base + (size_t)s * Sn + k] = eye;  // A^0 = I
    Pow[base + (size_t)(Sn * Sn) + (size_t)s * Sn + k] =
        eye + DT_STEP * Amat[(size_t)i * Sn * Sn + (size_t)s * Sn + k];
}

// Pc = Pa @ Pb, each 128x128 fp32. Block computes 64x32 quadrant.
__global__ __launch_bounds__(256) void pow_mul(float* __restrict__ Pow, int m, int kmax) {
    int job = blockIdx.z;
    int i  = job / kmax;
    int kk = job % kmax + 1;
    const float* Pa = Pow + ((size_t)i * NPOW + m) * (Sn * Sn);
    const float* Pb = Pow + ((size_t)i * NPOW + kk) * (Sn * Sn);
    float*       Pc = Pow + ((size_t)i * NPOW + m + kk) * (Sn * Sn);
    int r0 = blockIdx.y * 64, c0 = blockIdx.x * 32;
    __shared__ float Asl[64 * 129];
    __shared__ float Bsl[128 * 32];
    int tx = threadIdx.x, ty = threadIdx.y;
    int tid = ty * 16 + tx;
    for (int idx = tid; idx < 64 * 128; idx += 256) {
        int r = idx >> 7, cc = idx & 127;
        Asl[r * 129 + cc] = Pa[(size_t)(r0 + r) * 128 + cc];
    }
    for (int idx = tid; idx < 128 * 32; idx += 256) {
        int r = idx >> 5, cc = idx & 31;
        Bsl[r * 32 + cc] = Pb[(size_t)r * 128 + c0 + cc];
    }
    __syncthreads();
    float acc[4][2] = {{0.f,0.f},{0.f,0.f},{0.f,0.f},{0.f,0.f}};
    for (int k = 0; k < 128; k++) {
        float b0 = Bsl[k * 32 + tx * 2];
        float b1 = Bsl[k * 32 + tx * 2 + 1];
#pragma unroll
        for (int r = 0; r < 4; r++) {
            float a = Asl[(ty * 4 + r) * 129 + k];
            acc[r][0] += a * b0;
            acc[r][1] += a * b1;
        }
    }
#pragma unroll
    for (int r = 0; r < 4; r++) {
        Pc[(size_t)(r0 + ty * 4 + r) * 128 + c0 + tx * 2]     = acc[r][0];
        Pc[(size_t)(r0 + ty * 4 + r) * 128 + c0 + tx * 2 + 1] = acc[r][1];
    }
}

// ---------------------------------------------------------------------------
extern "C" void kernel_launch(void* const* d_in, const int* in_sizes, int n_in,
                              void* d_out, int out_size, void* d_ws, size_t ws_size,
                              hipStream_t stream) {
    const float* x     = (const float*)d_in[0];
    const float* Am    = (const float*)d_in[1];
    const float* Bp    = (const float*)d_in[2];
    const float* Cp    = (const float*)d_in[3];
    const float* Dp    = (const float*)d_in[4];
    const float* Wi    = (const float*)d_in[5];
    const float* bi    = (const float*)d_in[6];
    const float* Wo    = (const float*)d_in[7];
    const float* bo    = (const float*)d_in[8];
    const float* gamma = (const float*)d_in[9];
    const float* beta  = (const float*)d_in[10];
    float* out = (float*)d_out;
    (void)in_sizes; (void)n_in; (void)out_size; (void)ws_size;

    // Workspace layout (~107.4 MB)
    char* ws = (char*)d_ws;
    float*          seq   = (float*)(ws + (size_t)0);                 // 32 MB
    unsigned short* nbuf  = (unsigned short*)(ws + (size_t)33554432); // 16 MB
    // precompute-phase aliases inside nbuf region (dead before first ln_ub):
    unsigned short* WiTh  = (unsigned short*)(ws + (size_t)33554432); //  8 MB
    unsigned short* Woh   = (unsigned short*)(ws + (size_t)41943040); //  8 MB
    unsigned short* W4h   = (unsigned short*)(ws + (size_t)50331648); //  8 MB (Wo2@Wi)
    float*          boeff = (float*)(ws + (size_t)58720256);          // 16 KB
    float*          ub    = (float*)(ws + (size_t)67108864);          //  4 MB
    float*          hs    = (float*)(ws + (size_t)71303168);          //  4 MB
    unsigned short* hs_bf = (unsigned short*)(ws + (size_t)75497472); //  2 MB
    float*          Pow   = (float*)(ws + (size_t)77594624);          //  8.25 MB
    float*          carry = (float*)(ws + (size_t)86245376);          //  128 KB
    unsigned short* Wo2h  = (unsigned short*)(ws + (size_t)94765056); //  8 MB (Wo*Dp)
    unsigned short* Bph   = (unsigned short*)(ws + (size_t)103153664);//  1 MB
    unsigned short* CpTh  = (unsigned short*)(ws + (size_t)104202240);//  1 MB
    unsigned short* M2h   = (unsigned short*)(ws + (size_t)105250816);//  1 MB (DT*Bp@Wi)
    unsigned short* W3h   = (unsigned short*)(ws + (size_t)106299392);//  1 MB (Wo@Cp)
    float*          c2dt  = (float*)(ws + (size_t)107347968);         //  2 KB

    const long SW = (long)Sn * Dm;     // 128K

    // ---- precompute: converts + dot products (one launch) ----
    hipLaunchKernelGGL(prep_conv, dim3(2304, DEPTH), dim3(256), 0, stream,
                       Wo, Dp, Bp, bi, bo, Woh, Wo2h, Bph, c2dt, boeff);
    // transposes for Wi and Cp (one launch)
    hipLaunchKernelGGL(transpose_pre, dim3(36, 32, DEPTH), dim3(256), 0, stream,
                       Wi, WiTh, Cp, CpTh);

    // ---- precompute GEMMs: ONE launch, 320 blocks ----
    hipLaunchKernelGGL(gemm_pre, dim3(320), dim3(512), 0, stream,
                       Bph, WiTh, M2h, Woh, CpTh, W3h, Wo2h, W4h);

    // x (B,C,HW) -> seq (B,HW,C)
    hipLaunchKernelGGL(transpose_bll, dim3(32, 32, Bn), dim3(32, 32), 0, stream, x, seq);

    // Matrix powers of A_bar for all layers: I, A^1, then log-doubling
    hipLaunchKernelGGL(pow_init, dim3(DEPTH, Sn), dim3(Sn), 0, stream, Am, Pow);
    for (int m = 1; m < Qc; m <<= 1) {
        hipLaunchKernelGGL(pow_mul, dim3(4, 2, DEPTH * m), dim3(16, 16), 0, stream,
                           Pow, m, m);
    }

    for (int i = 0; i < DEPTH; i++) {
        const unsigned short* M2_i = M2h + (size_t)i * SW;
        const unsigned short* W3_i = W3h + (size_t)i * SW;
        const unsigned short* W4_i = W4h + (size_t)i * (size_t)(Dm * Dm);
        const float* PowL = Pow + (size_t)i * NPOW * (Sn * Sn);

        // LN + ub-GEMM fused (256 blocks)
        hipLaunchKernelGGL(ln_ub, dim3(256), dim3(512), 0, stream,
                           seq, nbuf, M2_i, ub, gamma + i * Dm, beta + i * Dm,
                           c2dt + i * Sn);
        // scan(256) interleaved with W4 tiles 0..255  [serial waves @ prio 1]
        hipLaunchKernelGGL(mega2, dim3(512), dim3(512), 0, stream,
                           0, nbuf, W4_i, seq, boeff + i * Dm,
                           ub, hs, hs_bf, PowL, carry);
        // carry(8) interleaved with W4 tiles 256..511
        hipLaunchKernelGGL(mega2, dim3(264), dim3(512), 0, stream,
                           1, nbuf, W4_i, seq, boeff + i * Dm,
                           ub, hs, hs_bf, PowL, carry);
        // fixup(256) interleaved with W4 tiles 512..1023
        hipLaunchKernelGGL(mega2, dim3(768), dim3(512), 0, stream,
                           2, nbuf, W4_i, seq, boeff + i * Dm,
                           ub, hs, hs_bf, PowL, carry);
        // seq += hs_bf @ W3^T (K=128) — own launch (RMW-disjointness with W4)
        hipLaunchKernelGGL(gemm_w3k, dim3(1024), dim3(512), 0, stream,
                           hs_bf, W3_i, seq);
    }

    // seq (B,HW,C) -> out (B,C,HW)
    hipLaunchKernelGGL(transpose_bll, dim3(32, 32, Bn), dim3(32, 32), 0, stream, seq, out);
}